// Round 6
// baseline (177.033 us; speedup 1.0000x reference)
//
#include <hip/hip_runtime.h>
#include <hip/hip_bf16.h>

#define S_LEN 8192
#define HID 768
#define NH 12
#define HD 64
#define WIN 256

typedef __bf16 bf16x8 __attribute__((ext_vector_type(8)));
typedef float f32x4 __attribute__((ext_vector_type(4)));
using bf16_t = __hip_bfloat16;

#define MFMA(a, b, c) __builtin_amdgcn_mfma_f32_16x16x32_bf16(a, b, c, 0, 0, 0)

// async global->LDS, 16B/lane; LDS dest is wave-uniform base (+lane*16 in HW)
__device__ __forceinline__ void gl2lds16(const bf16_t* g, bf16_t* l) {
  __builtin_amdgcn_global_load_lds(
      (const __attribute__((address_space(1))) void*)g,
      (__attribute__((address_space(3))) void*)l, 16, 0, 0);
}

// ---- prep: weight transpose only (R10: hs convert fused into qkv) -------
// 1728 blocks = 24x24x3 tiles of 32x32.
__global__ __launch_bounds__(256) void prep(const float* __restrict__ Wq,
                                            const float* __restrict__ Wk,
                                            const float* __restrict__ Wv,
                                            bf16_t* __restrict__ Wt) {
  __shared__ float t[32][33];
  int b = blockIdx.x;
  int tid = threadIdx.x;
  int z = b / 576;
  int r = b % 576;
  int n0 = (r / 24) * 32, k0 = (r % 24) * 32;
  const float* src = (z == 0) ? Wq : ((z == 1) ? Wk : Wv);
  int tx = tid & 31, ty = tid >> 5;  // 32 x 8
  for (int i = 0; i < 4; ++i)
    t[ty + i * 8][tx] = src[(k0 + ty + i * 8) * HID + n0 + tx];
  __syncthreads();
  bf16_t* dst = Wt + z * HID * HID;
  for (int i = 0; i < 4; ++i)
    dst[(n0 + ty + i * 8) * HID + k0 + tx] = __float2bfloat16(t[tx][ty + i * 8]);
}

// ---- fused QKV GEMM, 128x128 tile, BK=64, swizzled LDS ------------------
// R6 2-phase double-buffer + R9 XCD remap. R10: A read DIRECTLY from fp32
// hs with reg-staging (global->reg fp32 -> cvt -> swizzled ds_write_b128),
// eliminating the hb intermediate (prep convert pass + 12.6MB write +
// 12.6MB read). Loads issue before the MFMA cluster; cvt+ds_write after
// (compiler places the vmcnt wait there) -> latency hidden under compute.
// LDS layout identical to the gl2lds version: slot l&7 <- chunk
// (l&7)^(row&7), so fragment reads are unchanged. B stays on gl2lds16.
__global__ __launch_bounds__(256) void qkv_gemm(
    const float* __restrict__ hs, const bf16_t* __restrict__ Wt,
    const float* __restrict__ bq, const float* __restrict__ bk,
    const float* __restrict__ bv,
    bf16_t* __restrict__ Qw, bf16_t* __restrict__ Kw, bf16_t* __restrict__ Vt) {
  __shared__ __align__(16) bf16_t sA[2][128 * 64];
  __shared__ __align__(16) bf16_t sB[2][128 * 64];
  // bijective remap over 1152 blocks: b -> (xcd, mloc, n-step)
  int bl = blockIdx.y * 64 + blockIdx.x;
  int xcd = bl & 7;
  int j = bl >> 3;               // [0,144)
  int m0 = (xcd * 8 + (j & 7)) * 128;
  int rest = j >> 3;             // [0,18)
  int zq = rest / 6;
  int nn0 = (rest % 6) * 128;
  int n0g = zq * HID + nn0;
  int tid = threadIdx.x;
  int w = tid >> 6, lane = tid & 63, lm = lane & 15, qd = lane >> 4;
  int wm = w & 1, wn = w >> 1;

  int srow = w * 8 + (lane >> 3);                 // [0,32)
  int sc8 = (lane & 7) ^ ((lane >> 3) & 7);       // XOR-8 chunk swizzle
  const float* gAf = hs + (size_t)(m0 + srow) * HID + (lane & 7) * 8;
  const bf16_t* gB = Wt + (n0g + srow) * HID + sc8 * 8;
  int sx0 = lm & 7;
  // LDS elem base for this thread's A ds_writes (row-major [128][64],
  // row = srow + u*32, slot sc8):
  int awr = srow * 64 + sc8 * 8;

  float4 ra[8];  // in-flight fp32 A chunks (u=0..3, 2x float4 each)

#define QK_LOADA(kk)                                                   \
  {                                                                    \
    _Pragma("unroll") for (int u = 0; u < 4; ++u) {                    \
      const float* s = gAf + (u * 32) * HID + (kk);                    \
      ra[2 * u] = *reinterpret_cast<const float4*>(s);                 \
      ra[2 * u + 1] = *reinterpret_cast<const float4*>(s + 4);         \
    }                                                                  \
  }

#define QK_CVTWR(bb)                                                   \
  {                                                                    \
    _Pragma("unroll") for (int u = 0; u < 4; ++u) {                    \
      union { uint4 q; bf16_t b[8]; } T;                               \
      T.b[0] = __float2bfloat16(ra[2 * u].x);                          \
      T.b[1] = __float2bfloat16(ra[2 * u].y);                          \
      T.b[2] = __float2bfloat16(ra[2 * u].z);                          \
      T.b[3] = __float2bfloat16(ra[2 * u].w);                          \
      T.b[4] = __float2bfloat16(ra[2 * u + 1].x);                      \
      T.b[5] = __float2bfloat16(ra[2 * u + 1].y);                      \
      T.b[6] = __float2bfloat16(ra[2 * u + 1].z);                      \
      T.b[7] = __float2bfloat16(ra[2 * u + 1].w);                      \
      *reinterpret_cast<uint4*>(sA[bb] + u * 2048 + awr) = T.q;        \
    }                                                                  \
  }

#define QK_BSTG(kk, bb)                                                \
  {                                                                    \
    _Pragma("unroll") for (int u = 0; u < 4; ++u)                      \
      gl2lds16(gB + (u * 32) * HID + (kk), sB[bb] + u * 2048 + w * 512); \
  }

  // prologue: stage tile 0
  QK_LOADA(0);
  QK_BSTG(0, 0);
  QK_CVTWR(0);
  __syncthreads();

  f32x4 acc[4][4] = {};
  for (int kt = 0; kt < 12; ++kt) {
    int b = kt & 1;
    if (kt < 11) {
      QK_LOADA((kt + 1) * 64);
      QK_BSTG((kt + 1) * 64, b ^ 1);
    }
#pragma unroll
    for (int half = 0; half < 2; ++half) {
      int ca = (qd + 4 * half) ^ sx0;
      bf16x8 fa[4], fb[4];
#pragma unroll
      for (int i = 0; i < 4; ++i) {
        fa[i] = *reinterpret_cast<const bf16x8*>(
            sA[b] + (wm * 64 + i * 16 + lm) * 64 + ca * 8);
        fb[i] = *reinterpret_cast<const bf16x8*>(
            sB[b] + (wn * 64 + i * 16 + lm) * 64 + ca * 8);
      }
      if (zq == 2) {
#pragma unroll
        for (int i = 0; i < 4; ++i)
#pragma unroll
          for (int j2 = 0; j2 < 4; ++j2)
            acc[i][j2] = MFMA(fb[i], fa[j2], acc[i][j2]);  // C^T: rows=n
      } else {
#pragma unroll
        for (int i = 0; i < 4; ++i)
#pragma unroll
          for (int j2 = 0; j2 < 4; ++j2)
            acc[i][j2] = MFMA(fa[i], fb[j2], acc[i][j2]);  // rows=m
      }
    }
    if (kt < 11) QK_CVTWR(b ^ 1);  // vmcnt wait lands here, after MFMAs
    __syncthreads();  // drains B prefetch (RAW) + orders A ds_writes
  }

  if (zq != 2) {
    const float* bias = zq ? bk : bq;
    bf16_t* dst = zq ? Kw : Qw;
    float scale = zq ? 1.0f : 0.125f;  // fold 1/sqrt(D) into Q
#pragma unroll
    for (int j2 = 0; j2 < 4; ++j2) {
      int nl = nn0 + wn * 64 + j2 * 16 + lm;
      float bb = bias[nl];
      int h = nl >> 6, d = nl & 63;
#pragma unroll
      for (int i = 0; i < 4; ++i)
#pragma unroll
        for (int r = 0; r < 4; ++r) {
          int m = m0 + wm * 64 + i * 16 + qd * 4 + r;
          dst[(h * S_LEN + m) * HD + d] =
              __float2bfloat16((acc[i][j2][r] + bb) * scale);
        }
    }
  } else {
#pragma unroll
    for (int i = 0; i < 4; ++i)
#pragma unroll
      for (int r = 0; r < 4; ++r) {
        int nl = nn0 + wn * 64 + i * 16 + qd * 4 + r;  // nl == h*64+d
        float bb = bv[nl];
#pragma unroll
        for (int j2 = 0; j2 < 4; ++j2) {
          int m = m0 + wm * 64 + j2 * 16 + lm;
          Vt[nl * S_LEN + m] = __float2bfloat16(acc[i][j2][r] + bb);
        }
      }
  }
}

// ---- sliding-window attention, R8: 32 queries/wave (128/block) ----------
// K/V fragment reads + staging shared across both 16-query groups.
// LDS 48KB -> 3 blocks/CU; grid 64x12 = 768 = 3/CU x 256 CUs, no tail.
__global__ __launch_bounds__(256, 3) void swa_kernel(
    const bf16_t* __restrict__ Qw, const bf16_t* __restrict__ Kw,
    const bf16_t* __restrict__ Vt, float* __restrict__ out) {
  __shared__ __align__(16) bf16_t sK[2][64 * 64];   // [key][d], swizzled chunks
  __shared__ __align__(16) bf16_t sV[2][64 * 64];   // [d][key], swizzled chunks
  __shared__ __align__(16) bf16_t sP[4 * 32 * 64];  // per-wave, swizzled chunks
  int h = blockIdx.y;
  int nb = blockIdx.x;                              // [0,64)
  int q0 = (((nb & 7) << 3) | (nb >> 3)) * 128;     // XCD-contiguous q-tiles
  int tid = threadIdx.x;
  int w = tid >> 6, lane = tid & 63, lm = lane & 15, qd = lane >> 4;
  int xb = q0 + w * 32;

  // Q B-frags for both 16-query groups (col=query=lm, k=d)
  int qoff = (h * S_LEN + xb + lm) * HD + qd * 8;
  bf16x8 aq00 = *reinterpret_cast<const bf16x8*>(Qw + qoff);
  bf16x8 aq01 = *reinterpret_cast<const bf16x8*>(Qw + qoff + 32);
  bf16x8 aq10 = *reinterpret_cast<const bf16x8*>(Qw + qoff + 16 * HD);
  bf16x8 aq11 = *reinterpret_cast<const bf16x8*>(Qw + qoff + 16 * HD + 32);

  f32x4 o0[4] = {}, o1[4] = {};
  float lsum0 = 0.f, lsum1 = 0.f;  // per-lane partial denoms

  int y_begin = q0 - WIN; if (y_begin < 0) y_begin = 0;
  int y_end = q0 + 128 + WIN; if (y_end > S_LEN) y_end = S_LEN;
  int ntiles = (y_end - y_begin) >> 6;
  const bf16_t* Kh = Kw + h * S_LEN * HD;
  const bf16_t* Vh = Vt + h * HD * S_LEN;
  bf16_t* sPw = sP + w * 32 * 64;

  int srow = w * 8 + (lane >> 3);
  int sc8 = (lane & 7) ^ ((lane >> 3) & 7);
  int sx0 = lm & 7;

#define STAGE(y0, b)                                                    \
  {                                                                     \
    const bf16_t* kg = Kh + ((y0) + srow) * HD + sc8 * 8;               \
    gl2lds16(kg, &sK[b][w * 512]);                                      \
    gl2lds16(kg + 32 * HD, &sK[b][2048 + w * 512]);                     \
    const bf16_t* vg = Vh + srow * S_LEN + (y0) + sc8 * 8;              \
    gl2lds16(vg, &sV[b][w * 512]);                                      \
    gl2lds16(vg + 32 * S_LEN, &sV[b][2048 + w * 512]);                  \
  }

  STAGE(y_begin, 0);
  __syncthreads();

  for (int t = 0; t < ntiles; ++t) {
    int y0 = y_begin + t * 64;
    if (t + 1 < ntiles) STAGE(y0 + 64, (t + 1) & 1);
    int b = t & 1;
    // --- S^T = K.Q^T: rows=key (qd*4+r), cols=query (lm); K-frags shared
    f32x4 s0[4] = {}, s1[4] = {};
#pragma unroll
    for (int nt = 0; nt < 4; ++nt) {
      const bf16_t* kr = &sK[b][(nt * 16 + lm) * 64];
      bf16x8 b0 = *reinterpret_cast<const bf16x8*>(kr + (qd ^ sx0) * 8);
      bf16x8 b1 = *reinterpret_cast<const bf16x8*>(kr + ((qd + 4) ^ sx0) * 8);
      s0[nt] = MFMA(b0, aq00, s0[nt]);
      s0[nt] = MFMA(b1, aq01, s0[nt]);
      s1[nt] = MFMA(b0, aq10, s1[nt]);
      s1[nt] = MFMA(b1, aq11, s1[nt]);
    }
    // --- p = exp(s); mask only edge tiles (per-wave query span = 32)
    int dyw = y0 - xb;
    bool edge = (dyw > 193) || (dyw < -225);
#pragma unroll
    for (int g = 0; g < 2; ++g) {
      const f32x4* sg = g ? s1 : s0;
      float lacc = 0.f;
#pragma unroll
      for (int nt = 0; nt < 4; ++nt) {
        union { ushort4 u; bf16_t b[4]; } P;
#pragma unroll
        for (int r = 0; r < 4; ++r) {
          float pv;
          if (edge) {
            int dlt = (y0 + nt * 16 + qd * 4 + r) - (xb + g * 16 + lm);
            pv = (dlt <= WIN && dlt >= -WIN) ? __expf(sg[nt][r]) : 0.f;
          } else {
            pv = __expf(sg[nt][r]);
          }
          lacc += pv;
          P.b[r] = __float2bfloat16(pv);
        }
        *reinterpret_cast<ushort4*>(
            sPw + (g * 16 + lm) * 64 +
            (((2 * nt + (qd >> 1)) ^ sx0) * 8) + (qd & 1) * 4) = P.u;
      }
      if (g) lsum1 += lacc; else lsum0 += lacc;
    }
    // --- P A-frags (row=query=lm within group, k=key)
    bf16x8 ap00 =
        *reinterpret_cast<const bf16x8*>(sPw + lm * 64 + ((qd ^ sx0) * 8));
    bf16x8 ap01 = *reinterpret_cast<const bf16x8*>(sPw + lm * 64 +
                                                   (((qd + 4) ^ sx0) * 8));
    bf16x8 ap10 = *reinterpret_cast<const bf16x8*>(sPw + (16 + lm) * 64 +
                                                   ((qd ^ sx0) * 8));
    bf16x8 ap11 = *reinterpret_cast<const bf16x8*>(sPw + (16 + lm) * 64 +
                                                   (((qd + 4) ^ sx0) * 8));
    // --- O += P.V (rows=query, cols=d); V-frags shared across groups
#pragma unroll
    for (int nt = 0; nt < 4; ++nt) {
      const bf16_t* vr = &sV[b][(nt * 16 + lm) * 64];
      bf16x8 v0 = *reinterpret_cast<const bf16x8*>(vr + (qd ^ sx0) * 8);
      bf16x8 v1 = *reinterpret_cast<const bf16x8*>(vr + ((qd + 4) ^ sx0) * 8);
      o0[nt] = MFMA(ap00, v0, o0[nt]);
      o0[nt] = MFMA(ap01, v1, o0[nt]);
      o1[nt] = MFMA(ap10, v0, o1[nt]);
      o1[nt] = MFMA(ap11, v1, o1[nt]);
    }
    __syncthreads();  // drains prefetch + protects K/V buffers
  }
  // --- reduce lsum across the 4 qd-groups (query lives at lane lm)
  lsum0 += __shfl_xor(lsum0, 16);
  lsum0 += __shfl_xor(lsum0, 32);
  lsum1 += __shfl_xor(lsum1, 16);
  lsum1 += __shfl_xor(lsum1, 32);
  // --- normalize + store fp32; inv for row qd*4+r held at lane qd*4+r
#pragma unroll
  for (int r = 0; r < 4; ++r) {
    float inv0 = 1.f / __shfl(lsum0, qd * 4 + r);
    int x0 = xb + qd * 4 + r;
#pragma unroll
    for (int nt = 0; nt < 4; ++nt)
      out[x0 * HID + h * HD + nt * 16 + lm] = o0[nt][r] * inv0;
    float inv1 = 1.f / __shfl(lsum1, qd * 4 + r);
    int x1 = xb + 16 + qd * 4 + r;
#pragma unroll
    for (int nt = 0; nt < 4; ++nt)
      out[x1 * HID + h * HD + nt * 16 + lm] = o1[nt][r] * inv1;
  }
}

extern "C" void kernel_launch(void* const* d_in, const int* in_sizes, int n_in,
                              void* d_out, int out_size, void* d_ws, size_t ws_size,
                              hipStream_t stream) {
  const float* hs = (const float*)d_in[0];
  const float* Wq = (const float*)d_in[1];
  const float* bq = (const float*)d_in[2];
  const float* Wk = (const float*)d_in[3];
  const float* bk = (const float*)d_in[4];
  const float* Wv = (const float*)d_in[5];
  const float* bv = (const float*)d_in[6];
  float* out = (float*)d_out;

  const int NSH = S_LEN * HID;
  const int NW = 3 * HID * HID;
  bf16_t* p = (bf16_t*)d_ws;
  bf16_t* Wt = p; p += NW;
  bf16_t* Qw = p; p += NSH;
  bf16_t* Kw = p; p += NSH;
  bf16_t* Vt = p; p += NSH;

  prep<<<dim3(1728), dim3(256), 0, stream>>>(Wq, Wk, Wv, Wt);
  qkv_gemm<<<dim3(64, 18), dim3(256), 0, stream>>>(
      hs, Wt, bq, bk, bv, Qw, Kw, Vt);
  swa_kernel<<<dim3(64, 12), dim3(256), 0, stream>>>(Qw, Kw, Vt, out);
}

// Round 7
// 155.833 us; speedup vs baseline: 1.1360x; 1.1360x over previous
//
#include <hip/hip_runtime.h>
#include <hip/hip_bf16.h>

#define S_LEN 8192
#define HID 768
#define NH 12
#define HD 64
#define WIN 256

typedef __bf16 bf16x8 __attribute__((ext_vector_type(8)));
typedef float f32x4 __attribute__((ext_vector_type(4)));
using bf16_t = __hip_bfloat16;

#define MFMA(a, b, c) __builtin_amdgcn_mfma_f32_16x16x32_bf16(a, b, c, 0, 0, 0)

// async global->LDS, 16B/lane; LDS dest is wave-uniform base (+lane*16 in HW)
__device__ __forceinline__ void gl2lds16(const bf16_t* g, bf16_t* l) {
  __builtin_amdgcn_global_load_lds(
      (const __attribute__((address_space(1))) void*)g,
      (__attribute__((address_space(3))) void*)l, 16, 0, 0);
}

// ---- prep: fused hs fp32->bf16 convert + weight transpose ---------------
// R11: restored (R6's convert-into-qkv fusion refetched fp32 A -> reverted).
// blocks [0, 6144): convert; blocks [6144, 7872): transpose (24x24x3).
__global__ __launch_bounds__(256) void prep(const float* __restrict__ hs,
                                            bf16_t* __restrict__ hb,
                                            const float* __restrict__ Wq,
                                            const float* __restrict__ Wk,
                                            const float* __restrict__ Wv,
                                            bf16_t* __restrict__ Wt) {
  int bx = blockIdx.x;
  int tid = threadIdx.x;
  if (bx < 6144) {
    int i = (bx * 256 + tid) * 4;
    float4 v = *reinterpret_cast<const float4*>(hs + i);
    union { ushort4 u; bf16_t b[4]; } H;
    H.b[0] = __float2bfloat16(v.x);
    H.b[1] = __float2bfloat16(v.y);
    H.b[2] = __float2bfloat16(v.z);
    H.b[3] = __float2bfloat16(v.w);
    *reinterpret_cast<ushort4*>(hb + i) = H.u;
    return;
  }
  __shared__ float t[32][33];
  int b = bx - 6144;
  int z = b / 576;
  int r = b % 576;
  int n0 = (r / 24) * 32, k0 = (r % 24) * 32;
  const float* src = (z == 0) ? Wq : ((z == 1) ? Wk : Wv);
  int tx = tid & 31, ty = tid >> 5;  // 32 x 8
  for (int i = 0; i < 4; ++i)
    t[ty + i * 8][tx] = src[(k0 + ty + i * 8) * HID + n0 + tx];
  __syncthreads();
  bf16_t* dst = Wt + z * HID * HID;
  for (int i = 0; i < 4; ++i)
    dst[(n0 + ty + i * 8) * HID + k0 + tx] = __float2bfloat16(t[tx][ty + i * 8]);
}

// ---- fused QKV GEMM, R11: 64x128 tile, BK=64, 3 blocks/CU ---------------
// Same R6-proven 2-phase double-buffer inner loop + R9 XCD remap. Tile
// shrunk 128x128 -> 64x128: LDS 64->48KB -> 3 blocks/CU (12 waves/CU,
// +50% TLP on a latency-bound kernel; m114 inter-block-slip mechanism).
// Grid 2304 = 3 exact rounds of 256 CUs x 3 blocks. Per-wave MFMA/K-step
// unchanged (16); VGPR drops (acc 64->32 AGPR).
__global__ __launch_bounds__(256, 3) void qkv_gemm(
    const bf16_t* __restrict__ hb, const bf16_t* __restrict__ Wt,
    const float* __restrict__ bq, const float* __restrict__ bk,
    const float* __restrict__ bv,
    bf16_t* __restrict__ Qw, bf16_t* __restrict__ Kw, bf16_t* __restrict__ Vt) {
  __shared__ __align__(16) bf16_t sA[2][64 * 64];   // 16KB
  __shared__ __align__(16) bf16_t sB[2][128 * 64];  // 32KB
  // bijective remap over 2304 blocks: bl -> (xcd, 16 m-tiles, 18 n-steps)
  int bl = blockIdx.y * 128 + blockIdx.x;
  int xcd = bl & 7;
  int j = bl >> 3;                 // [0,288)
  int m0 = (xcd * 16 + (j & 15)) * 64;
  int rest = j >> 4;               // [0,18)
  int zq = rest / 6;
  int nn0 = (rest % 6) * 128;
  int n0g = zq * HID + nn0;
  int tid = threadIdx.x;
  int w = tid >> 6, lane = tid & 63, lm = lane & 15, qd = lane >> 4;
  int wm = w & 1, wn = w >> 1;     // 2m x 2n waves, 32x64 out each

  int srow = w * 8 + (lane >> 3);                 // [0,32)
  int sc8 = (lane & 7) ^ ((lane >> 3) & 7);       // XOR-8 chunk swizzle
  const bf16_t* gA = hb + (m0 + srow) * HID + sc8 * 8;
  const bf16_t* gB = Wt + (n0g + srow) * HID + sc8 * 8;
  int sx0 = lm & 7;

#define QSTAGE(kk, bb)                                                       \
  {                                                                          \
    _Pragma("unroll") for (int u = 0; u < 2; ++u)                            \
        gl2lds16(gA + (u * 32) * HID + (kk), sA[bb] + u * 2048 + w * 512);   \
    _Pragma("unroll") for (int u = 0; u < 4; ++u)                            \
        gl2lds16(gB + (u * 32) * HID + (kk), sB[bb] + u * 2048 + w * 512);   \
  }

  QSTAGE(0, 0);
  __syncthreads();

  f32x4 acc[8] = {};  // zq!=2: [i(2)][j(4)] = i*4+j ; zq==2: [j(4)][i(2)] = j*2+i
  for (int kt = 0; kt < 12; ++kt) {
    int b = kt & 1;
    if (kt < 11) QSTAGE((kt + 1) * 64, b ^ 1);
#pragma unroll
    for (int half = 0; half < 2; ++half) {
      int ca = (qd + 4 * half) ^ sx0;
      bf16x8 fa[2], fb[4];
#pragma unroll
      for (int i = 0; i < 2; ++i)
        fa[i] = *reinterpret_cast<const bf16x8*>(
            sA[b] + (wm * 32 + i * 16 + lm) * 64 + ca * 8);
#pragma unroll
      for (int i = 0; i < 4; ++i)
        fb[i] = *reinterpret_cast<const bf16x8*>(
            sB[b] + (wn * 64 + i * 16 + lm) * 64 + ca * 8);
      if (zq == 2) {
#pragma unroll
        for (int j2 = 0; j2 < 4; ++j2)
#pragma unroll
          for (int i = 0; i < 2; ++i)
            acc[j2 * 2 + i] = MFMA(fb[j2], fa[i], acc[j2 * 2 + i]);  // C^T
      } else {
#pragma unroll
        for (int i = 0; i < 2; ++i)
#pragma unroll
          for (int j2 = 0; j2 < 4; ++j2)
            acc[i * 4 + j2] = MFMA(fa[i], fb[j2], acc[i * 4 + j2]);  // rows=m
      }
    }
    __syncthreads();  // drains prefetch (RAW) + protects read buffer (WAR)
  }

  if (zq != 2) {
    const float* bias = zq ? bk : bq;
    bf16_t* dst = zq ? Kw : Qw;
    float scale = zq ? 1.0f : 0.125f;  // fold 1/sqrt(D) into Q
#pragma unroll
    for (int j2 = 0; j2 < 4; ++j2) {
      int nl = nn0 + wn * 64 + j2 * 16 + lm;
      float bb = bias[nl];
      int h = nl >> 6, d = nl & 63;
#pragma unroll
      for (int i = 0; i < 2; ++i)
#pragma unroll
        for (int r = 0; r < 4; ++r) {
          int m = m0 + wm * 32 + i * 16 + qd * 4 + r;
          dst[(h * S_LEN + m) * HD + d] =
              __float2bfloat16((acc[i * 4 + j2][r] + bb) * scale);
        }
    }
  } else {
#pragma unroll
    for (int j2 = 0; j2 < 4; ++j2)
#pragma unroll
      for (int r = 0; r < 4; ++r) {
        int nl = nn0 + wn * 64 + j2 * 16 + qd * 4 + r;  // nl == h*64+d
        float bb = bv[nl];
#pragma unroll
        for (int i = 0; i < 2; ++i) {
          int m = m0 + wm * 32 + i * 16 + lm;
          Vt[nl * S_LEN + m] = __float2bfloat16(acc[j2 * 2 + i][r] + bb);
        }
      }
  }
}

// ---- sliding-window attention, R8: 32 queries/wave (128/block) ----------
// K/V fragment reads + staging shared across both 16-query groups.
// LDS 48KB -> 3 blocks/CU; grid 64x12 = 768 = 3/CU x 256 CUs, no tail.
__global__ __launch_bounds__(256, 3) void swa_kernel(
    const bf16_t* __restrict__ Qw, const bf16_t* __restrict__ Kw,
    const bf16_t* __restrict__ Vt, float* __restrict__ out) {
  __shared__ __align__(16) bf16_t sK[2][64 * 64];   // [key][d], swizzled chunks
  __shared__ __align__(16) bf16_t sV[2][64 * 64];   // [d][key], swizzled chunks
  __shared__ __align__(16) bf16_t sP[4 * 32 * 64];  // per-wave, swizzled chunks
  int h = blockIdx.y;
  int nb = blockIdx.x;                              // [0,64)
  int q0 = (((nb & 7) << 3) | (nb >> 3)) * 128;     // XCD-contiguous q-tiles
  int tid = threadIdx.x;
  int w = tid >> 6, lane = tid & 63, lm = lane & 15, qd = lane >> 4;
  int xb = q0 + w * 32;

  // Q B-frags for both 16-query groups (col=query=lm, k=d)
  int qoff = (h * S_LEN + xb + lm) * HD + qd * 8;
  bf16x8 aq00 = *reinterpret_cast<const bf16x8*>(Qw + qoff);
  bf16x8 aq01 = *reinterpret_cast<const bf16x8*>(Qw + qoff + 32);
  bf16x8 aq10 = *reinterpret_cast<const bf16x8*>(Qw + qoff + 16 * HD);
  bf16x8 aq11 = *reinterpret_cast<const bf16x8*>(Qw + qoff + 16 * HD + 32);

  f32x4 o0[4] = {}, o1[4] = {};
  float lsum0 = 0.f, lsum1 = 0.f;  // per-lane partial denoms

  int y_begin = q0 - WIN; if (y_begin < 0) y_begin = 0;
  int y_end = q0 + 128 + WIN; if (y_end > S_LEN) y_end = S_LEN;
  int ntiles = (y_end - y_begin) >> 6;
  const bf16_t* Kh = Kw + h * S_LEN * HD;
  const bf16_t* Vh = Vt + h * HD * S_LEN;
  bf16_t* sPw = sP + w * 32 * 64;

  int srow = w * 8 + (lane >> 3);
  int sc8 = (lane & 7) ^ ((lane >> 3) & 7);
  int sx0 = lm & 7;

#define STAGE(y0, b)                                                    \
  {                                                                     \
    const bf16_t* kg = Kh + ((y0) + srow) * HD + sc8 * 8;               \
    gl2lds16(kg, &sK[b][w * 512]);                                      \
    gl2lds16(kg + 32 * HD, &sK[b][2048 + w * 512]);                     \
    const bf16_t* vg = Vh + srow * S_LEN + (y0) + sc8 * 8;              \
    gl2lds16(vg, &sV[b][w * 512]);                                      \
    gl2lds16(vg + 32 * S_LEN, &sV[b][2048 + w * 512]);                  \
  }

  STAGE(y_begin, 0);
  __syncthreads();

  for (int t = 0; t < ntiles; ++t) {
    int y0 = y_begin + t * 64;
    if (t + 1 < ntiles) STAGE(y0 + 64, (t + 1) & 1);
    int b = t & 1;
    // --- S^T = K.Q^T: rows=key (qd*4+r), cols=query (lm); K-frags shared
    f32x4 s0[4] = {}, s1[4] = {};
#pragma unroll
    for (int nt = 0; nt < 4; ++nt) {
      const bf16_t* kr = &sK[b][(nt * 16 + lm) * 64];
      bf16x8 b0 = *reinterpret_cast<const bf16x8*>(kr + (qd ^ sx0) * 8);
      bf16x8 b1 = *reinterpret_cast<const bf16x8*>(kr + ((qd + 4) ^ sx0) * 8);
      s0[nt] = MFMA(b0, aq00, s0[nt]);
      s0[nt] = MFMA(b1, aq01, s0[nt]);
      s1[nt] = MFMA(b0, aq10, s1[nt]);
      s1[nt] = MFMA(b1, aq11, s1[nt]);
    }
    // --- p = exp(s); mask only edge tiles (per-wave query span = 32)
    int dyw = y0 - xb;
    bool edge = (dyw > 193) || (dyw < -225);
#pragma unroll
    for (int g = 0; g < 2; ++g) {
      const f32x4* sg = g ? s1 : s0;
      float lacc = 0.f;
#pragma unroll
      for (int nt = 0; nt < 4; ++nt) {
        union { ushort4 u; bf16_t b[4]; } P;
#pragma unroll
        for (int r = 0; r < 4; ++r) {
          float pv;
          if (edge) {
            int dlt = (y0 + nt * 16 + qd * 4 + r) - (xb + g * 16 + lm);
            pv = (dlt <= WIN && dlt >= -WIN) ? __expf(sg[nt][r]) : 0.f;
          } else {
            pv = __expf(sg[nt][r]);
          }
          lacc += pv;
          P.b[r] = __float2bfloat16(pv);
        }
        *reinterpret_cast<ushort4*>(
            sPw + (g * 16 + lm) * 64 +
            (((2 * nt + (qd >> 1)) ^ sx0) * 8) + (qd & 1) * 4) = P.u;
      }
      if (g) lsum1 += lacc; else lsum0 += lacc;
    }
    // --- P A-frags (row=query=lm within group, k=key)
    bf16x8 ap00 =
        *reinterpret_cast<const bf16x8*>(sPw + lm * 64 + ((qd ^ sx0) * 8));
    bf16x8 ap01 = *reinterpret_cast<const bf16x8*>(sPw + lm * 64 +
                                                   (((qd + 4) ^ sx0) * 8));
    bf16x8 ap10 = *reinterpret_cast<const bf16x8*>(sPw + (16 + lm) * 64 +
                                                   ((qd ^ sx0) * 8));
    bf16x8 ap11 = *reinterpret_cast<const bf16x8*>(sPw + (16 + lm) * 64 +
                                                   (((qd + 4) ^ sx0) * 8));
    // --- O += P.V (rows=query, cols=d); V-frags shared across groups
#pragma unroll
    for (int nt = 0; nt < 4; ++nt) {
      const bf16_t* vr = &sV[b][(nt * 16 + lm) * 64];
      bf16x8 v0 = *reinterpret_cast<const bf16x8*>(vr + (qd ^ sx0) * 8);
      bf16x8 v1 = *reinterpret_cast<const bf16x8*>(vr + ((qd + 4) ^ sx0) * 8);
      o0[nt] = MFMA(ap00, v0, o0[nt]);
      o0[nt] = MFMA(ap01, v1, o0[nt]);
      o1[nt] = MFMA(ap10, v0, o1[nt]);
      o1[nt] = MFMA(ap11, v1, o1[nt]);
    }
    __syncthreads();  // drains prefetch + protects K/V buffers
  }
  // --- reduce lsum across the 4 qd-groups (query lives at lane lm)
  lsum0 += __shfl_xor(lsum0, 16);
  lsum0 += __shfl_xor(lsum0, 32);
  lsum1 += __shfl_xor(lsum1, 16);
  lsum1 += __shfl_xor(lsum1, 32);
  // --- normalize + store fp32; inv for row qd*4+r held at lane qd*4+r
#pragma unroll
  for (int r = 0; r < 4; ++r) {
    float inv0 = 1.f / __shfl(lsum0, qd * 4 + r);
    int x0 = xb + qd * 4 + r;
#pragma unroll
    for (int nt = 0; nt < 4; ++nt)
      out[x0 * HID + h * HD + nt * 16 + lm] = o0[nt][r] * inv0;
    float inv1 = 1.f / __shfl(lsum1, qd * 4 + r);
    int x1 = xb + 16 + qd * 4 + r;
#pragma unroll
    for (int nt = 0; nt < 4; ++nt)
      out[x1 * HID + h * HD + nt * 16 + lm] = o1[nt][r] * inv1;
  }
}

extern "C" void kernel_launch(void* const* d_in, const int* in_sizes, int n_in,
                              void* d_out, int out_size, void* d_ws, size_t ws_size,
                              hipStream_t stream) {
  const float* hs = (const float*)d_in[0];
  const float* Wq = (const float*)d_in[1];
  const float* bq = (const float*)d_in[2];
  const float* Wk = (const float*)d_in[3];
  const float* bk = (const float*)d_in[4];
  const float* Wv = (const float*)d_in[5];
  const float* bv = (const float*)d_in[6];
  float* out = (float*)d_out;

  const int NSH = S_LEN * HID;
  const int NW = 3 * HID * HID;
  bf16_t* p = (bf16_t*)d_ws;
  bf16_t* hb = p; p += NSH;
  bf16_t* Wt = p; p += NW;
  bf16_t* Qw = p; p += NSH;
  bf16_t* Kw = p; p += NSH;
  bf16_t* Vt = p; p += NSH;

  prep<<<dim3(6144 + 1728), dim3(256), 0, stream>>>(hs, hb, Wq, Wk, Wv, Wt);
  qkv_gemm<<<dim3(128, 18), dim3(256), 0, stream>>>(
      hb, Wt, bq, bk, bv, Qw, Kw, Vt);
  swa_kernel<<<dim3(64, 12), dim3(256), 0, stream>>>(Qw, Kw, Vt, out);
}